// Round 18
// baseline (190.435 us; speedup 1.0000x reference)
//
#include <hip/hip_runtime.h>
#include <stdint.h>

// MHA fwd: B=4,S=2048,E=1024,H=16,D=64. fp32 in/out, bf16 MFMA internally.
// pack_all -> GEMM1 split: QK (256x256 2-buf vmcnt(8), 256 blocks = 1 exact round)
//   + V (128x256 3-buf dist-2 4-phase, 256 blocks = 1 exact round)
// -> attn (swapped-QK^T, in-reg P, fixed-shift softmax; PAIRED chunks: each block
//   does qb=31-j then qb=j -> uniform 33 steps, 1024 blocks = 4/CU exact round)
// -> GEMM2 (out proj, 128x256 structure).

typedef float   f32x4  __attribute__((ext_vector_type(4)));
typedef __bf16  bf16x8 __attribute__((ext_vector_type(8)));
typedef short   short8 __attribute__((ext_vector_type(8)));
typedef unsigned short ushort4v __attribute__((ext_vector_type(4)));

typedef __attribute__((address_space(1))) void GV;
typedef __attribute__((address_space(3))) void LV;

#define DEVI static __device__ __forceinline__

DEVI unsigned short f2bf(float f){
  unsigned u = __float_as_uint(f);
  unsigned r = u + 0x7fffu + ((u>>16)&1u);
  return (unsigned short)(r>>16);
}

DEVI unsigned cvt_pk_bf16(float lo, float hi){
  unsigned r;
  asm("v_cvt_pk_bf16_f32 %0, %1, %2" : "=v"(r) : "v"(lo), "v"(hi));
  return r;
}

DEVI void permlane32_swap(unsigned &a, unsigned &b){
  asm volatile("v_permlane32_swap_b32 %0, %1" : "+v"(a), "+v"(b));
}
DEVI void permlane16_swap(unsigned &a, unsigned &b){
  asm volatile("v_permlane16_swap_b32 %0, %1" : "+v"(a), "+v"(b));
}

DEVI void gl_lds16(const void* g, void* l){
  __builtin_amdgcn_global_load_lds((GV*)g, (LV*)l, 16, 0, 0);
}

#define BAR() asm volatile("s_barrier" ::: "memory")

// ---------------- merged pack kernel ----------------
__global__ __launch_bounds__(256)
void pack_all(const float* __restrict__ X,
              const float* __restrict__ Wq, const float* __restrict__ Wk,
              const float* __restrict__ Wv, const float* __restrict__ Wo,
              short* __restrict__ Xb, short* __restrict__ Wp,
              short* __restrict__ WoT)
{
  int bid = blockIdx.x;
  if (bid < 4096){
    int i = bid*256 + threadIdx.x;
    const float4* p = (const float4*)(X + (size_t)i*8);
    float4 a = p[0], b = p[1];
    short8 o;
    o[0]=(short)f2bf(a.x); o[1]=(short)f2bf(a.y); o[2]=(short)f2bf(a.z); o[3]=(short)f2bf(a.w);
    o[4]=(short)f2bf(b.x); o[5]=(short)f2bf(b.y); o[6]=(short)f2bf(b.z); o[7]=(short)f2bf(b.w);
    *(short8*)(Xb + (size_t)i*8) = o;
  } else if (bid < 5632){
    int t = (bid - 4096)*256 + threadIdx.x;
    int n = t >> 7, kc = t & 127;
    int which = n >> 10, hd = n & 1023, h = hd >> 6, d = hd & 63;
    const float* W = which==0 ? Wq : (which==1 ? Wk : Wv);
    const float* src = W + ((size_t)h*1024 + kc*8)*64 + d;
    short8 o;
    #pragma unroll
    for (int j=0;j<8;++j) o[j] = (short)f2bf(src[(size_t)j*64]);
    *(short8*)(Wp + (size_t)n*1024 + kc*8) = o;
  } else {
    int t = (bid - 5632)*256 + threadIdx.x;
    int n = t >> 7, kc = t & 127;
    const float* src = Wo + (size_t)(kc*8)*1024 + n;
    short8 o;
    #pragma unroll
    for (int j=0;j<8;++j) o[j] = (short)f2bf(src[(size_t)j*1024]);
    *(short8*)(WoT + (size_t)n*1024 + kc*8) = o;
  }
}

// ------- GEMM1a: QK[8192][2048] = Xbf * Wp[0:2048]^T, 256x256 tile, BK=64 -------
__global__ __launch_bounds__(512)
void gemm_qk(const short* __restrict__ A, const short* __restrict__ Bt,
             const float* __restrict__ b0, const float* __restrict__ b1,
             short* __restrict__ Qb, short* __restrict__ Kb)
{
  __shared__ __align__(16) char sm[2][65536];   // per buf: A 32KB | B 32KB
  const int K2 = 2048;
  int t = threadIdx.x, lane = t & 63, wid = t >> 6;
  int wr = wid >> 2, wc = wid & 3;
  int l15 = lane & 15, l4 = lane >> 4;
  int swz = (blockIdx.x & 7) * 32 + (blockIdx.x >> 3);   // 256 blocks, XCD swizzle
  int bm = swz & 31, bn = swz >> 5;                      // 32 x 8
  size_t abase = (size_t)bm * 256 * K2;
  size_t bbase = (size_t)bn * 256 * K2;

  f32x4 acc[8][4] = {};
  bf16x8 af[8], bfr[4];
  const char* sA; const char* sB;

  auto stageA = [&](int kt, char* buf){
    int kb = kt * 128;
    #pragma unroll
    for (int c = 0; c < 4; ++c){
      int x = c*8192 + t*16;
      int r = x >> 7, z = x & 127;
      int zs = z ^ ((r & 7) << 4);
      gl_lds16((const char*)A + abase + (size_t)r*K2 + kb + zs, buf + c*8192 + wid*1024);
    }
  };
  auto stageB = [&](int kt, char* buf){
    int kb = kt * 128;
    #pragma unroll
    for (int c = 0; c < 4; ++c){
      int x = c*8192 + t*16;
      int r = x >> 7, z = x & 127;
      int zs = z ^ ((r & 7) << 4);
      gl_lds16((const char*)Bt + bbase + (size_t)r*K2 + kb + zs, buf + 32768 + c*8192 + wid*1024);
    }
  };
  auto rd_af = [&](int kk){
    int cb = kk*64 + l4*16;
    #pragma unroll
    for (int i = 0; i < 8; ++i){
      int ra = wr*128 + i*16 + l15;
      af[i] = *(const bf16x8*)(sA + ra*128 + (cb ^ ((ra&7)<<4)));
    }
  };
  auto rd_bf = [&](int kk){
    int cb = kk*64 + l4*16;
    #pragma unroll
    for (int j = 0; j < 4; ++j){
      int rb = wc*64 + j*16 + l15;
      bfr[j] = *(const bf16x8*)(sB + rb*128 + (cb ^ ((rb&7)<<4)));
    }
  };
  auto mm = [&](){
    __builtin_amdgcn_s_setprio(1);
    #pragma unroll
    for (int i = 0; i < 8; ++i)
      #pragma unroll
      for (int j = 0; j < 4; ++j)
        acc[i][j] = __builtin_amdgcn_mfma_f32_16x16x32_bf16(af[i], bfr[j], acc[i][j], 0, 0, 0);
    __builtin_amdgcn_s_setprio(0);
  };

  stageA(0, sm[0]); stageB(0, sm[0]);

  for (int kt = 0; kt < 16; ++kt){
    BAR();
    if (kt < 15){
      char* nb = sm[(kt + 1) & 1];
      stageA(kt + 1, nb); stageB(kt + 1, nb);
      asm volatile("s_waitcnt vmcnt(8)" ::: "memory");
    } else {
      asm volatile("s_waitcnt vmcnt(0)" ::: "memory");
    }
    BAR();
    sA = sm[kt & 1]; sB = sA + 32768;
    rd_af(0); rd_bf(0);
    mm();
    rd_af(1); rd_bf(1);
    mm();
  }

  #pragma unroll
  for (int i = 0; i < 8; ++i){
    int mbase = bm*256 + wr*128 + i*16 + l4*4;
    #pragma unroll
    for (int j = 0; j < 4; ++j){
      int n = bn*256 + wc*64 + j*16 + l15;
      int which = n >> 10, hd = n & 1023, h = hd >> 6, d = hd & 63;
      float bias = (which==0 ? b0 : b1)[hd];
      int b = mbase >> 11, sbase = mbase & 2047;
      size_t bh = (size_t)(b*16 + h);
      short* dst = (which==0 ? Qb : Kb) + bh*2048*64;
      float sc = which==0 ? 0.18033688f : 1.0f;   // Q: 1/sqrt(D)*log2(e)
      #pragma unroll
      for (int r = 0; r < 4; ++r)
        dst[(size_t)(sbase + r)*64 + d] = (short)f2bf((acc[i][j][r] + bias) * sc);
    }
  }
}

// ------- GEMM (128x256, 3-buf dist-2 4-phase counted vmcnt(6)) -------
// MODE 1: out-proj epilogue (fp32 +bias). MODE 2: V epilogue (bf16, transposed).
template<int MODE>
__global__ __launch_bounds__(512)
void gemm256(const short* __restrict__ A, const short* __restrict__ Bt,
             const float* __restrict__ b0,
             short* __restrict__ Vtb, float* __restrict__ Out)
{
  __shared__ __align__(16) char sm[3][49152];   // per buf: A 16KB | B 32KB
  const int K2 = 2048;
  int t = threadIdx.x, lane = t & 63, wid = t >> 6;
  int wr = wid >> 2, wc = wid & 3;
  int l15 = lane & 15, l4 = lane >> 4;
  int nwg = gridDim.x, qd = nwg >> 3;
  int swz = (blockIdx.x & 7) * qd + (blockIdx.x >> 3);
  int bm = swz & 63, bn = swz >> 6;
  size_t abase = (size_t)bm * 128 * K2;
  size_t bbase = (size_t)bn * 256 * K2;

  f32x4 acc[4][4] = {};
  const char* sA; const char* sB;
  bf16x8 af[4], bfr[4];

  auto stageA = [&](int kt, char* buf){
    int kb = kt * 128;
    #pragma unroll
    for (int c = 0; c < 2; ++c){
      int x = c*8192 + t*16;
      int r = x >> 7, z = x & 127;
      int zs = z ^ ((r & 7) << 4);
      gl_lds16((const char*)A + abase + (size_t)r*K2 + kb + zs, buf + c*8192 + wid*1024);
    }
  };
  auto stageB = [&](int kt, char* buf, int c0){
    int kb = kt * 128;
    #pragma unroll
    for (int c = 0; c < 2; ++c){
      int cc = c0 + c;
      int x = cc*8192 + t*16;
      int r = x >> 7, z = x & 127;
      int zs = z ^ ((r & 7) << 4);
      gl_lds16((const char*)Bt + bbase + (size_t)r*K2 + kb + zs, buf + 16384 + cc*8192 + wid*1024);
    }
  };
  auto rd_af = [&](int kk){
    int cb = kk*64 + l4*16;
    #pragma unroll
    for (int i = 0; i < 4; ++i){
      int ra = wr*64 + i*16 + l15;
      af[i] = *(const bf16x8*)(sA + ra*128 + (cb ^ ((ra&7)<<4)));
    }
  };
  auto rd_bf = [&](int kk, int j0){
    int cb = kk*64 + l4*16;
    #pragma unroll
    for (int j = 0; j < 2; ++j){
      int rb = wc*64 + (j0 + j)*16 + l15;
      bfr[j0 + j] = *(const bf16x8*)(sB + rb*128 + (cb ^ ((rb&7)<<4)));
    }
  };
  auto mm = [&](int j0){
    __builtin_amdgcn_s_setprio(1);
    #pragma unroll
    for (int i = 0; i < 4; ++i)
      #pragma unroll
      for (int j = 0; j < 2; ++j)
        acc[i][j0+j] = __builtin_amdgcn_mfma_f32_16x16x32_bf16(af[i], bfr[j0+j], acc[i][j0+j], 0, 0, 0);
    __builtin_amdgcn_s_setprio(0);
  };

  stageA(0, sm[0]); stageB(0, sm[0], 0); stageB(0, sm[0], 2);
  stageA(1, sm[1]); stageB(1, sm[1], 0); stageB(1, sm[1], 2);

  for (int kt = 0; kt < 16; ++kt){
    if (kt == 15) asm volatile("s_waitcnt vmcnt(0)" ::: "memory");
    else          asm volatile("s_waitcnt vmcnt(6)" ::: "memory");
    BAR();
    sA = sm[kt % 3]; sB = sA + 16384;
    char* nb = sm[(kt + 2) % 3];
    bool st = kt < 14;
    rd_af(0); rd_bf(0, 0);
    if (st) stageA(kt + 2, nb);
    BAR(); mm(0); BAR();
    rd_bf(0, 2);
    if (st) stageB(kt + 2, nb, 0);
    BAR(); mm(2); BAR();
    rd_af(1); rd_bf(1, 0);
    if (st) stageB(kt + 2, nb, 2);
    BAR(); mm(0); BAR();
    rd_bf(1, 2);
    BAR(); mm(2);
  }

  #pragma unroll
  for (int i = 0; i < 4; ++i){
    int mbase = bm*128 + wr*64 + i*16 + l4*4;
    #pragma unroll
    for (int j = 0; j < 4; ++j){
      int n = bn*256 + wc*64 + j*16 + l15;
      if (MODE == 2){
        int h = n >> 6, d = n & 63;
        float bias = b0[n];
        int b = mbase >> 11, sbase = mbase & 2047;
        size_t bh = (size_t)(b*16 + h);
        ushort4v pv;
        #pragma unroll
        for (int r = 0; r < 4; ++r) pv[r] = f2bf(acc[i][j][r] + bias);
        *(ushort4v*)(Vtb + (bh*64 + d)*2048 + sbase) = pv;
      } else {
        float bias = b0[n];
        #pragma unroll
        for (int r = 0; r < 4; ++r)
          Out[(size_t)(mbase + r)*1024 + n] = acc[i][j][r] + bias;
      }
    }
  }
}

// ---------------- causal flash attention (paired chunks, uniform blocks) ----------------
// grid: 1024 blocks = 64 bh x 16 pairs; block runs qb=31-j then qb=j (33 steps total).
// 4 blocks/CU = exactly one full-chip round, no tail. 4 waves x 16 q-rows per chunk.
// Swapped QK^T; P in registers via permlane swaps; fixed-shift softmax.
__global__ __launch_bounds__(256, 5)
void attn(const short* __restrict__ Qb, const short* __restrict__ Kb,
          const short* __restrict__ Vtb, short* __restrict__ Ob)
{
  __shared__ __align__(16) char smK[2][8192];
  __shared__ __align__(16) char smV[2][8192];
  int t = threadIdx.x, lane = t & 63, wid = t >> 6;
  int l15 = lane & 15, hi = lane >> 4;
  int hi16 = hi*16, hi4 = hi*4;
  int bh = blockIdx.x & 63;
  int j = blockIdx.x >> 6;                   // 0..15
  int b = bh >> 4, h = bh & 15;
  const char* Qh = (const char*)(Qb + (size_t)bh*2048*64);
  const char* Kh = (const char*)(Kb + (size_t)bh*2048*64);
  const char* Vh = (const char*)(Vtb + (size_t)bh*64*2048);

  bf16x8 vones;
  #pragma unroll
  for (int z = 0; z < 8; ++z) vones[z] = (__bf16)1.0f;

  for (int half = 0; half < 2; ++half){
    int qb = half ? j : (31 - j);            // long chunk first
    int wq0 = qb*64 + wid*16;
    int nkt = qb + 1;

    bf16x8 qf[2];
    #pragma unroll
    for (int kk = 0; kk < 2; ++kk)
      qf[kk] = *(const bf16x8*)(Qh + (size_t)(wq0 + l15)*128 + kk*64 + hi16);

    f32x4 oacc[4] = {};
    f32x4 lacc = {};

    // prologue: stage tile 0 into buffer 0 (safe: previous chunk's loop ended
    // with __syncthreads after all LDS reads)
    #pragma unroll
    for (int c = 0; c < 2; ++c){
      int x = c*4096 + t*16;
      int r = x >> 7, z = x & 127;
      int zs = z ^ ((r & 7) << 4);
      gl_lds16(Kh + (size_t)r*128 + zs, smK[0] + c*4096 + wid*1024);
      gl_lds16(Vh + (size_t)r*4096 + zs, smV[0] + c*4096 + wid*1024);
    }
    __syncthreads();

    for (int kt = 0; kt < nkt; ++kt){
      int cur = kt & 1;
      if (kt + 1 < nkt){
        int nxt = cur ^ 1;
        #pragma unroll
        for (int c = 0; c < 2; ++c){
          int x = c*4096 + t*16;
          int r = x >> 7, z = x & 127;
          int zs = z ^ ((r & 7) << 4);
          gl_lds16(Kh + (size_t)(kt+1)*8192 + (size_t)r*128 + zs, smK[nxt] + c*4096 + wid*1024);
          gl_lds16(Vh + (size_t)r*4096 + (size_t)(kt+1)*128 + zs, smV[nxt] + c*4096 + wid*1024);
        }
      }
      const char* Kc = smK[cur];
      const char* Vc = smV[cur];
      int kbase = kt * 64;

      f32x4 sa[4];
      __builtin_amdgcn_s_setprio(1);
      #pragma unroll
      for (int nt = 0; nt < 4; ++nt){
        f32x4 a = {};
        #pragma unroll
        for (int kk = 0; kk < 2; ++kk){
          int rk = nt*16 + l15;
          bf16x8 kf = *(const bf16x8*)(Kc + rk*128 + ((kk*64 + hi16) ^ ((rk&7)<<4)));
          a = __builtin_amdgcn_mfma_f32_16x16x32_bf16(kf, qf[kk], a, 0, 0, 0);
        }
        sa[nt] = a;
      }
      __builtin_amdgcn_s_setprio(0);

      if (kt == qb){
        int qrow = wq0 + l15;
        #pragma unroll
        for (int nt = 0; nt < 4; ++nt)
          #pragma unroll
          for (int r = 0; r < 4; ++r)
            if (kbase + nt*16 + hi4 + r > qrow) sa[nt][r] = -1e30f;
      }

      unsigned pw[8];
      #pragma unroll
      for (int nt = 0; nt < 4; ++nt){
        float p0 = exp2f(sa[nt][0]);
        float p1 = exp2f(sa[nt][1]);
        float p2 = exp2f(sa[nt][2]);
        float p3 = exp2f(sa[nt][3]);
        pw[nt*2]   = cvt_pk_bf16(p0, p1);
        pw[nt*2+1] = cvt_pk_bf16(p2, p3);
      }

      union U { unsigned u[4]; bf16x8 v; } f0, f1;
      {
        unsigned a0 = pw[0], b0v = pw[2];
        permlane32_swap(a0, b0v); permlane16_swap(a0, b0v);
        unsigned a1 = pw[1], b1v = pw[3];
        permlane32_swap(a1, b1v); permlane16_swap(a1, b1v);
        f0.u[0] = a0; f0.u[1] = a1; f0.u[2] = b0v; f0.u[3] = b1v;
        unsigned a2 = pw[4], b2v = pw[6];
        permlane32_swap(a2, b2v); permlane16_swap(a2, b2v);
        unsigned a3 = pw[5], b3v = pw[7];
        permlane32_swap(a3, b3v); permlane16_swap(a3, b3v);
        f1.u[0] = a2; f1.u[1] = a3; f1.u[2] = b2v; f1.u[3] = b3v;
      }

      __builtin_amdgcn_s_setprio(1);
      #pragma unroll
      for (int kk = 0; kk < 2; ++kk){
        bf16x8 pf = kk ? f1.v : f0.v;
        lacc = __builtin_amdgcn_mfma_f32_16x16x32_bf16(vones, pf, lacc, 0, 0, 0);
        #pragma unroll
        for (int dt = 0; dt < 4; ++dt){
          int rv = dt*16 + l15;
          bf16x8 vf = *(const bf16x8*)(Vc + rv*128 + ((kk*64 + hi16) ^ ((rv&7)<<4)));
          oacc[dt] = __builtin_amdgcn_mfma_f32_16x16x32_bf16(vf, pf, oacc[dt], 0, 0, 0);
        }
      }
      __builtin_amdgcn_s_setprio(0);

      __syncthreads();
    }

    // write O (concat layout [b][s][h*64+d]) in bf16
    float inv = 1.0f / lacc[0];
    int srow = wq0 + l15;
    size_t rb = ((size_t)(b*2048 + srow))*1024 + h*64 + hi4;
    #pragma unroll
    for (int dt = 0; dt < 4; ++dt){
      unsigned w0 = cvt_pk_bf16(oacc[dt][0]*inv, oacc[dt][1]*inv);
      unsigned w1 = cvt_pk_bf16(oacc[dt][2]*inv, oacc[dt][3]*inv);
      *(unsigned long long*)(Ob + rb + dt*16) =
          ((unsigned long long)w1 << 32) | (unsigned long long)w0;
    }
  }
}

// ---------------- launch ----------------
extern "C" void kernel_launch(void* const* d_in, const int* in_sizes, int n_in,
                              void* d_out, int out_size, void* d_ws, size_t ws_size,
                              hipStream_t stream)
{
  const float* X  = (const float*)d_in[0];
  const float* Wq = (const float*)d_in[1];
  const float* Wk = (const float*)d_in[2];
  const float* Wv = (const float*)d_in[3];
  const float* bq = (const float*)d_in[4];
  const float* bk = (const float*)d_in[5];
  const float* bv = (const float*)d_in[6];
  const float* Wo = (const float*)d_in[7];
  const float* bo = (const float*)d_in[8];
  float* Out = (float*)d_out;

  char* ws = (char*)d_ws;
  short* Xbf  = (short*)(ws);
  short* Wp   = (short*)(ws + 16777216);
  short* WoT  = (short*)(ws + 23068672);
  short* Qb   = (short*)(ws + 25165824);
  short* Kb   = (short*)(ws + 41943040);
  short* Vtb  = (short*)(ws + 58720256);
  short* Ob   = (short*)(ws + 75497472);

  pack_all<<<6144, 256, 0, stream>>>(X, Wq, Wk, Wv, Wo, Xbf, Wp, WoT);

  gemm_qk   <<<256, 512, 0, stream>>>(Xbf, Wp, bq, bk, Qb, Kb);
  gemm256<2><<<256, 512, 0, stream>>>(Xbf, Wp + (size_t)2048*1024, bv, Vtb, nullptr);
  attn      <<<1024, 256, 0, stream>>>(Qb, Kb, Vtb, Ob);
  gemm256<1><<<256, 512, 0, stream>>>(Ob, WoT, bo, nullptr, Out);
}

// Round 19
// 183.769 us; speedup vs baseline: 1.0363x; 1.0363x over previous
//
#include <hip/hip_runtime.h>
#include <stdint.h>

// MHA fwd: B=4,S=2048,E=1024,H=16,D=64. fp32 in/out, bf16 MFMA internally.
// pack_all -> GEMM1 split: QK (256x256 2-buf vmcnt(8), 256 blocks = 1 exact round)
//   + V (128x256 3-buf dist-2 4-phase, 256 blocks = 1 exact round)
// -> attn (swapped-QK^T, in-reg P, fixed-shift softmax, QBLK=64, LPT, 2048 blocks)
// -> GEMM2 (out proj, 128x256 structure).
// Final configuration = round-17 best (184.2 us measured).

typedef float   f32x4  __attribute__((ext_vector_type(4)));
typedef __bf16  bf16x8 __attribute__((ext_vector_type(8)));
typedef short   short8 __attribute__((ext_vector_type(8)));
typedef unsigned short ushort4v __attribute__((ext_vector_type(4)));

typedef __attribute__((address_space(1))) void GV;
typedef __attribute__((address_space(3))) void LV;

#define DEVI static __device__ __forceinline__

DEVI unsigned short f2bf(float f){
  unsigned u = __float_as_uint(f);
  unsigned r = u + 0x7fffu + ((u>>16)&1u);
  return (unsigned short)(r>>16);
}

DEVI unsigned cvt_pk_bf16(float lo, float hi){
  unsigned r;
  asm("v_cvt_pk_bf16_f32 %0, %1, %2" : "=v"(r) : "v"(lo), "v"(hi));
  return r;
}

DEVI void permlane32_swap(unsigned &a, unsigned &b){
  asm volatile("v_permlane32_swap_b32 %0, %1" : "+v"(a), "+v"(b));
}
DEVI void permlane16_swap(unsigned &a, unsigned &b){
  asm volatile("v_permlane16_swap_b32 %0, %1" : "+v"(a), "+v"(b));
}

DEVI void gl_lds16(const void* g, void* l){
  __builtin_amdgcn_global_load_lds((GV*)g, (LV*)l, 16, 0, 0);
}

#define BAR() asm volatile("s_barrier" ::: "memory")

// ---------------- merged pack kernel ----------------
__global__ __launch_bounds__(256)
void pack_all(const float* __restrict__ X,
              const float* __restrict__ Wq, const float* __restrict__ Wk,
              const float* __restrict__ Wv, const float* __restrict__ Wo,
              short* __restrict__ Xb, short* __restrict__ Wp,
              short* __restrict__ WoT)
{
  int bid = blockIdx.x;
  if (bid < 4096){
    int i = bid*256 + threadIdx.x;
    const float4* p = (const float4*)(X + (size_t)i*8);
    float4 a = p[0], b = p[1];
    short8 o;
    o[0]=(short)f2bf(a.x); o[1]=(short)f2bf(a.y); o[2]=(short)f2bf(a.z); o[3]=(short)f2bf(a.w);
    o[4]=(short)f2bf(b.x); o[5]=(short)f2bf(b.y); o[6]=(short)f2bf(b.z); o[7]=(short)f2bf(b.w);
    *(short8*)(Xb + (size_t)i*8) = o;
  } else if (bid < 5632){
    int t = (bid - 4096)*256 + threadIdx.x;
    int n = t >> 7, kc = t & 127;
    int which = n >> 10, hd = n & 1023, h = hd >> 6, d = hd & 63;
    const float* W = which==0 ? Wq : (which==1 ? Wk : Wv);
    const float* src = W + ((size_t)h*1024 + kc*8)*64 + d;
    short8 o;
    #pragma unroll
    for (int j=0;j<8;++j) o[j] = (short)f2bf(src[(size_t)j*64]);
    *(short8*)(Wp + (size_t)n*1024 + kc*8) = o;
  } else {
    int t = (bid - 5632)*256 + threadIdx.x;
    int n = t >> 7, kc = t & 127;
    const float* src = Wo + (size_t)(kc*8)*1024 + n;
    short8 o;
    #pragma unroll
    for (int j=0;j<8;++j) o[j] = (short)f2bf(src[(size_t)j*1024]);
    *(short8*)(WoT + (size_t)n*1024 + kc*8) = o;
  }
}

// ------- GEMM1a: QK[8192][2048] = Xbf * Wp[0:2048]^T, 256x256 tile, BK=64 -------
// 8 waves 2Mx4N (per-wave 128x64). 2 LDS buffers (128KB), XOR-swizzled 128B rows,
// counted vmcnt(8): BAR(free) -> issue next tile -> vmcnt(8) -> BAR(ready).
// grid 256 = 32x8 = exactly 1 full-chip round.
__global__ __launch_bounds__(512)
void gemm_qk(const short* __restrict__ A, const short* __restrict__ Bt,
             const float* __restrict__ b0, const float* __restrict__ b1,
             short* __restrict__ Qb, short* __restrict__ Kb)
{
  __shared__ __align__(16) char sm[2][65536];   // per buf: A 32KB | B 32KB
  const int K2 = 2048;
  int t = threadIdx.x, lane = t & 63, wid = t >> 6;
  int wr = wid >> 2, wc = wid & 3;
  int l15 = lane & 15, l4 = lane >> 4;
  int swz = (blockIdx.x & 7) * 32 + (blockIdx.x >> 3);   // 256 blocks, XCD swizzle
  int bm = swz & 31, bn = swz >> 5;                      // 32 x 8
  size_t abase = (size_t)bm * 256 * K2;
  size_t bbase = (size_t)bn * 256 * K2;

  f32x4 acc[8][4] = {};
  bf16x8 af[8], bfr[4];
  const char* sA; const char* sB;

  auto stageA = [&](int kt, char* buf){
    int kb = kt * 128;
    #pragma unroll
    for (int c = 0; c < 4; ++c){
      int x = c*8192 + t*16;
      int r = x >> 7, z = x & 127;
      int zs = z ^ ((r & 7) << 4);
      gl_lds16((const char*)A + abase + (size_t)r*K2 + kb + zs, buf + c*8192 + wid*1024);
    }
  };
  auto stageB = [&](int kt, char* buf){
    int kb = kt * 128;
    #pragma unroll
    for (int c = 0; c < 4; ++c){
      int x = c*8192 + t*16;
      int r = x >> 7, z = x & 127;
      int zs = z ^ ((r & 7) << 4);
      gl_lds16((const char*)Bt + bbase + (size_t)r*K2 + kb + zs, buf + 32768 + c*8192 + wid*1024);
    }
  };
  auto rd_af = [&](int kk){
    int cb = kk*64 + l4*16;
    #pragma unroll
    for (int i = 0; i < 8; ++i){
      int ra = wr*128 + i*16 + l15;
      af[i] = *(const bf16x8*)(sA + ra*128 + (cb ^ ((ra&7)<<4)));
    }
  };
  auto rd_bf = [&](int kk){
    int cb = kk*64 + l4*16;
    #pragma unroll
    for (int j = 0; j < 4; ++j){
      int rb = wc*64 + j*16 + l15;
      bfr[j] = *(const bf16x8*)(sB + rb*128 + (cb ^ ((rb&7)<<4)));
    }
  };
  auto mm = [&](){
    __builtin_amdgcn_s_setprio(1);
    #pragma unroll
    for (int i = 0; i < 8; ++i)
      #pragma unroll
      for (int j = 0; j < 4; ++j)
        acc[i][j] = __builtin_amdgcn_mfma_f32_16x16x32_bf16(af[i], bfr[j], acc[i][j], 0, 0, 0);
    __builtin_amdgcn_s_setprio(0);
  };

  stageA(0, sm[0]); stageB(0, sm[0]);

  for (int kt = 0; kt < 16; ++kt){
    BAR();                                      // buf[(kt+1)&1] free (all waves)
    if (kt < 15){
      char* nb = sm[(kt + 1) & 1];
      stageA(kt + 1, nb); stageB(kt + 1, nb);
      asm volatile("s_waitcnt vmcnt(8)" ::: "memory");   // tile kt landed; kt+1 in flight
    } else {
      asm volatile("s_waitcnt vmcnt(0)" ::: "memory");
    }
    BAR();                                      // tile kt ready (all waves)
    sA = sm[kt & 1]; sB = sA + 32768;
    rd_af(0); rd_bf(0);
    mm();
    rd_af(1); rd_bf(1);
    mm();
  }

  // epilogue: Q (n<1024, pre-scaled) / K row-major [s][d]
  #pragma unroll
  for (int i = 0; i < 8; ++i){
    int mbase = bm*256 + wr*128 + i*16 + l4*4;
    #pragma unroll
    for (int j = 0; j < 4; ++j){
      int n = bn*256 + wc*64 + j*16 + l15;
      int which = n >> 10, hd = n & 1023, h = hd >> 6, d = hd & 63;
      float bias = (which==0 ? b0 : b1)[hd];
      int b = mbase >> 11, sbase = mbase & 2047;
      size_t bh = (size_t)(b*16 + h);
      short* dst = (which==0 ? Qb : Kb) + bh*2048*64;
      float sc = which==0 ? 0.18033688f : 1.0f;   // Q: 1/sqrt(D)*log2(e)
      #pragma unroll
      for (int r = 0; r < 4; ++r)
        dst[(size_t)(sbase + r)*64 + d] = (short)f2bf((acc[i][j][r] + bias) * sc);
    }
  }
}

// ------- GEMM (128x256, 3-buf dist-2 4-phase counted vmcnt(6)) -------
// MODE 1: out-proj epilogue (fp32 +bias). MODE 2: V epilogue (bf16, transposed).
template<int MODE>
__global__ __launch_bounds__(512)
void gemm256(const short* __restrict__ A, const short* __restrict__ Bt,
             const float* __restrict__ b0,
             short* __restrict__ Vtb, float* __restrict__ Out)
{
  __shared__ __align__(16) char sm[3][49152];   // per buf: A 16KB | B 32KB
  const int K2 = 2048;
  int t = threadIdx.x, lane = t & 63, wid = t >> 6;
  int wr = wid >> 2, wc = wid & 3;
  int l15 = lane & 15, l4 = lane >> 4;
  int nwg = gridDim.x, qd = nwg >> 3;
  int swz = (blockIdx.x & 7) * qd + (blockIdx.x >> 3);
  int bm = swz & 63, bn = swz >> 6;
  size_t abase = (size_t)bm * 128 * K2;
  size_t bbase = (size_t)bn * 256 * K2;

  f32x4 acc[4][4] = {};
  const char* sA; const char* sB;
  bf16x8 af[4], bfr[4];

  auto stageA = [&](int kt, char* buf){
    int kb = kt * 128;
    #pragma unroll
    for (int c = 0; c < 2; ++c){
      int x = c*8192 + t*16;
      int r = x >> 7, z = x & 127;
      int zs = z ^ ((r & 7) << 4);
      gl_lds16((const char*)A + abase + (size_t)r*K2 + kb + zs, buf + c*8192 + wid*1024);
    }
  };
  auto stageB = [&](int kt, char* buf, int c0){
    int kb = kt * 128;
    #pragma unroll
    for (int c = 0; c < 2; ++c){
      int cc = c0 + c;
      int x = cc*8192 + t*16;
      int r = x >> 7, z = x & 127;
      int zs = z ^ ((r & 7) << 4);
      gl_lds16((const char*)Bt + bbase + (size_t)r*K2 + kb + zs, buf + 16384 + cc*8192 + wid*1024);
    }
  };
  auto rd_af = [&](int kk){
    int cb = kk*64 + l4*16;
    #pragma unroll
    for (int i = 0; i < 4; ++i){
      int ra = wr*64 + i*16 + l15;
      af[i] = *(const bf16x8*)(sA + ra*128 + (cb ^ ((ra&7)<<4)));
    }
  };
  auto rd_bf = [&](int kk, int j0){
    int cb = kk*64 + l4*16;
    #pragma unroll
    for (int j = 0; j < 2; ++j){
      int rb = wc*64 + (j0 + j)*16 + l15;
      bfr[j0 + j] = *(const bf16x8*)(sB + rb*128 + (cb ^ ((rb&7)<<4)));
    }
  };
  auto mm = [&](int j0){
    __builtin_amdgcn_s_setprio(1);
    #pragma unroll
    for (int i = 0; i < 4; ++i)
      #pragma unroll
      for (int j = 0; j < 2; ++j)
        acc[i][j0+j] = __builtin_amdgcn_mfma_f32_16x16x32_bf16(af[i], bfr[j0+j], acc[i][j0+j], 0, 0, 0);
    __builtin_amdgcn_s_setprio(0);
  };

  stageA(0, sm[0]); stageB(0, sm[0], 0); stageB(0, sm[0], 2);
  stageA(1, sm[1]); stageB(1, sm[1], 0); stageB(1, sm[1], 2);

  for (int kt = 0; kt < 16; ++kt){
    if (kt == 15) asm volatile("s_waitcnt vmcnt(0)" ::: "memory");
    else          asm volatile("s_waitcnt vmcnt(6)" ::: "memory");
    BAR();
    sA = sm[kt % 3]; sB = sA + 16384;
    char* nb = sm[(kt + 2) % 3];
    bool st = kt < 14;
    rd_af(0); rd_bf(0, 0);
    if (st) stageA(kt + 2, nb);
    BAR(); mm(0); BAR();
    rd_bf(0, 2);
    if (st) stageB(kt + 2, nb, 0);
    BAR(); mm(2); BAR();
    rd_af(1); rd_bf(1, 0);
    if (st) stageB(kt + 2, nb, 2);
    BAR(); mm(0); BAR();
    rd_bf(1, 2);
    BAR(); mm(2);
  }

  #pragma unroll
  for (int i = 0; i < 4; ++i){
    int mbase = bm*128 + wr*64 + i*16 + l4*4;
    #pragma unroll
    for (int j = 0; j < 4; ++j){
      int n = bn*256 + wc*64 + j*16 + l15;
      if (MODE == 2){
        // V epilogue: n == hd in [0,1024); write V^T [b,h][d][s] in bf16
        int h = n >> 6, d = n & 63;
        float bias = b0[n];
        int b = mbase >> 11, sbase = mbase & 2047;
        size_t bh = (size_t)(b*16 + h);
        ushort4v pv;
        #pragma unroll
        for (int r = 0; r < 4; ++r) pv[r] = f2bf(acc[i][j][r] + bias);
        *(ushort4v*)(Vtb + (bh*64 + d)*2048 + sbase) = pv;
      } else {
        float bias = b0[n];
        #pragma unroll
        for (int r = 0; r < 4; ++r)
          Out[(size_t)(mbase + r)*1024 + n] = acc[i][j][r] + bias;
      }
    }
  }
}

// ---------------- causal flash attention ----------------
// grid: 2048 blocks = 32 q-chunks (LPT) x 64 bh; 4 waves x 16 q-rows (QBLK=64).
// Swapped QK^T; P in registers via permlane swaps; fixed-shift softmax
// (P=exp2(s) directly, l via all-ones MFMA; masked -> exp2(-1e30)=0).
__global__ __launch_bounds__(256, 5)
void attn(const short* __restrict__ Qb, const short* __restrict__ Kb,
          const short* __restrict__ Vtb, short* __restrict__ Ob)
{
  __shared__ __align__(16) char smK[2][8192];
  __shared__ __align__(16) char smV[2][8192];
  int t = threadIdx.x, lane = t & 63, wid = t >> 6;
  int l15 = lane & 15, hi = lane >> 4;
  int hi16 = hi*16, hi4 = hi*4;
  int bh = blockIdx.x & 63;
  int qb = 31 - (blockIdx.x >> 6);           // LPT: longest first
  int b = bh >> 4, h = bh & 15;
  int wq0 = qb*64 + wid*16;
  const char* Qh = (const char*)(Qb + (size_t)bh*2048*64);
  const char* Kh = (const char*)(Kb + (size_t)bh*2048*64);
  const char* Vh = (const char*)(Vtb + (size_t)bh*64*2048);

  bf16x8 vones;
  #pragma unroll
  for (int z = 0; z < 8; ++z) vones[z] = (__bf16)1.0f;

  bf16x8 qf[2];
  #pragma unroll
  for (int kk = 0; kk < 2; ++kk)
    qf[kk] = *(const bf16x8*)(Qh + (size_t)(wq0 + l15)*128 + kk*64 + hi16);

  f32x4 oacc[4] = {};
  f32x4 lacc = {};

  int nkt = qb + 1;

  #pragma unroll
  for (int c = 0; c < 2; ++c){
    int x = c*4096 + t*16;
    int r = x >> 7, z = x & 127;
    int zs = z ^ ((r & 7) << 4);
    gl_lds16(Kh + (size_t)r*128 + zs, smK[0] + c*4096 + wid*1024);
    gl_lds16(Vh + (size_t)r*4096 + zs, smV[0] + c*4096 + wid*1024);
  }
  __syncthreads();

  for (int kt = 0; kt < nkt; ++kt){
    int cur = kt & 1;
    if (kt + 1 < nkt){
      int nxt = cur ^ 1;
      #pragma unroll
      for (int c = 0; c < 2; ++c){
        int x = c*4096 + t*16;
        int r = x >> 7, z = x & 127;
        int zs = z ^ ((r & 7) << 4);
        gl_lds16(Kh + (size_t)(kt+1)*8192 + (size_t)r*128 + zs, smK[nxt] + c*4096 + wid*1024);
        gl_lds16(Vh + (size_t)r*4096 + (size_t)(kt+1)*128 + zs, smV[nxt] + c*4096 + wid*1024);
      }
    }
    const char* Kc = smK[cur];
    const char* Vc = smV[cur];
    int kbase = kt * 64;

    f32x4 sa[4];
    __builtin_amdgcn_s_setprio(1);
    #pragma unroll
    for (int nt = 0; nt < 4; ++nt){
      f32x4 a = {};
      #pragma unroll
      for (int kk = 0; kk < 2; ++kk){
        int rk = nt*16 + l15;
        bf16x8 kf = *(const bf16x8*)(Kc + rk*128 + ((kk*64 + hi16) ^ ((rk&7)<<4)));
        a = __builtin_amdgcn_mfma_f32_16x16x32_bf16(kf, qf[kk], a, 0, 0, 0);
      }
      sa[nt] = a;
    }
    __builtin_amdgcn_s_setprio(0);

    if (kt == qb){
      int qrow = wq0 + l15;
      #pragma unroll
      for (int nt = 0; nt < 4; ++nt)
        #pragma unroll
        for (int r = 0; r < 4; ++r)
          if (kbase + nt*16 + hi4 + r > qrow) sa[nt][r] = -1e30f;
    }

    unsigned pw[8];
    #pragma unroll
    for (int nt = 0; nt < 4; ++nt){
      float p0 = exp2f(sa[nt][0]);
      float p1 = exp2f(sa[nt][1]);
      float p2 = exp2f(sa[nt][2]);
      float p3 = exp2f(sa[nt][3]);
      pw[nt*2]   = cvt_pk_bf16(p0, p1);
      pw[nt*2+1] = cvt_pk_bf16(p2, p3);
    }

    union U { unsigned u[4]; bf16x8 v; } f0, f1;
    {
      unsigned a0 = pw[0], b0v = pw[2];
      permlane32_swap(a0, b0v); permlane16_swap(a0, b0v);
      unsigned a1 = pw[1], b1v = pw[3];
      permlane32_swap(a1, b1v); permlane16_swap(a1, b1v);
      f0.u[0] = a0; f0.u[1] = a1; f0.u[2] = b0v; f0.u[3] = b1v;
      unsigned a2 = pw[4], b2v = pw[6];
      permlane32_swap(a2, b2v); permlane16_swap(a2, b2v);
      unsigned a3 = pw[5], b3v = pw[7];
      permlane32_swap(a3, b3v); permlane16_swap(a3, b3v);
      f1.u[0] = a2; f1.u[1] = a3; f1.u[2] = b2v; f1.u[3] = b3v;
    }

    __builtin_amdgcn_s_setprio(1);
    #pragma unroll
    for (int kk = 0; kk < 2; ++kk){
      bf16x8 pf = kk ? f1.v : f0.v;
      lacc = __builtin_amdgcn_mfma_f32_16x16x32_bf16(vones, pf, lacc, 0, 0, 0);
      #pragma unroll
      for (int dt = 0; dt < 4; ++dt){
        int rv = dt*16 + l15;
        bf16x8 vf = *(const bf16x8*)(Vc + rv*128 + ((kk*64 + hi16) ^ ((rv&7)<<4)));
        oacc[dt] = __builtin_amdgcn_mfma_f32_16x16x32_bf16(vf, pf, oacc[dt], 0, 0, 0);
      }
    }
    __builtin_amdgcn_s_setprio(0);

    __syncthreads();
  }

  float inv = 1.0f / lacc[0];
  int srow = wq0 + l15;
  size_t rb = ((size_t)(b*2048 + srow))*1024 + h*64 + hi4;
  #pragma unroll
  for (int dt = 0; dt < 4; ++dt){
    unsigned w0 = cvt_pk_bf16(oacc[dt][0]*inv, oacc[dt][1]*inv);
    unsigned w1 = cvt_pk_bf16(oacc[dt][2]*inv, oacc[dt][3]*inv);
    *(unsigned long long*)(Ob + rb + dt*16) =
        ((unsigned long long)w1 << 32) | (unsigned long long)w0;
  }
}

// ---------------- launch ----------------
extern "C" void kernel_launch(void* const* d_in, const int* in_sizes, int n_in,
                              void* d_out, int out_size, void* d_ws, size_t ws_size,
                              hipStream_t stream)
{
  const float* X  = (const float*)d_in[0];
  const float* Wq = (const float*)d_in[1];
  const float* Wk = (const float*)d_in[2];
  const float* Wv = (const float*)d_in[3];
  const float* bq = (const float*)d_in[4];
  const float* bk = (const float*)d_in[5];
  const float* bv = (const float*)d_in[6];
  const float* Wo = (const float*)d_in[7];
  const float* bo = (const float*)d_in[8];
  float* Out = (float*)d_out;

  char* ws = (char*)d_ws;
  short* Xbf  = (short*)(ws);
  short* Wp   = (short*)(ws + 16777216);
  short* WoT  = (short*)(ws + 23068672);
  short* Qb   = (short*)(ws + 25165824);
  short* Kb   = (short*)(ws + 41943040);
  short* Vtb  = (short*)(ws + 58720256);
  short* Ob   = (short*)(ws + 75497472);

  pack_all<<<6144, 256, 0, stream>>>(X, Wq, Wk, Wv, Wo, Xbf, Wp, WoT);

  // GEMM1 split: QK (256^2, 1 exact round) + V (128x256, 1 exact round)
  gemm_qk   <<<256, 512, 0, stream>>>(Xbf, Wp, bq, bk, Qb, Kb);
  gemm256<2><<<256, 512, 0, stream>>>(Xbf, Wp + (size_t)2048*1024, bv, Vtb, nullptr);
  attn      <<<2048, 256, 0, stream>>>(Qb, Kb, Vtb, Ob);
  gemm256<1><<<256, 512, 0, stream>>>(Ob, WoT, bo, nullptr, Out);
}

// Round 20
// 183.167 us; speedup vs baseline: 1.0397x; 1.0033x over previous
//
#include <hip/hip_runtime.h>
#include <stdint.h>

// MHA fwd: B=4,S=2048,E=1024,H=16,D=64. fp32 in/out, bf16 MFMA internally.
// pack_all -> gemm_qkv (merged: blocks 0-255 QK path 256x256 2-buf vmcnt(8);
//   blocks 256-511 V path 128x256 3-buf dist-2 vmcnt(6)) -> attn -> gemm_out.

typedef float   f32x4  __attribute__((ext_vector_type(4)));
typedef __bf16  bf16x8 __attribute__((ext_vector_type(8)));
typedef short   short8 __attribute__((ext_vector_type(8)));
typedef unsigned short ushort4v __attribute__((ext_vector_type(4)));

typedef __attribute__((address_space(1))) void GV;
typedef __attribute__((address_space(3))) void LV;

#define DEVI static __device__ __forceinline__

DEVI unsigned short f2bf(float f){
  unsigned u = __float_as_uint(f);
  unsigned r = u + 0x7fffu + ((u>>16)&1u);
  return (unsigned short)(r>>16);
}

DEVI unsigned cvt_pk_bf16(float lo, float hi){
  unsigned r;
  asm("v_cvt_pk_bf16_f32 %0, %1, %2" : "=v"(r) : "v"(lo), "v"(hi));
  return r;
}

DEVI void permlane32_swap(unsigned &a, unsigned &b){
  asm volatile("v_permlane32_swap_b32 %0, %1" : "+v"(a), "+v"(b));
}
DEVI void permlane16_swap(unsigned &a, unsigned &b){
  asm volatile("v_permlane16_swap_b32 %0, %1" : "+v"(a), "+v"(b));
}

DEVI void gl_lds16(const void* g, void* l){
  __builtin_amdgcn_global_load_lds((GV*)g, (LV*)l, 16, 0, 0);
}

#define BAR() asm volatile("s_barrier" ::: "memory")

// ---------------- merged pack kernel ----------------
__global__ __launch_bounds__(256)
void pack_all(const float* __restrict__ X,
              const float* __restrict__ Wq, const float* __restrict__ Wk,
              const float* __restrict__ Wv, const float* __restrict__ Wo,
              short* __restrict__ Xb, short* __restrict__ Wp,
              short* __restrict__ WoT)
{
  int bid = blockIdx.x;
  if (bid < 4096){
    int i = bid*256 + threadIdx.x;
    const float4* p = (const float4*)(X + (size_t)i*8);
    float4 a = p[0], b = p[1];
    short8 o;
    o[0]=(short)f2bf(a.x); o[1]=(short)f2bf(a.y); o[2]=(short)f2bf(a.z); o[3]=(short)f2bf(a.w);
    o[4]=(short)f2bf(b.x); o[5]=(short)f2bf(b.y); o[6]=(short)f2bf(b.z); o[7]=(short)f2bf(b.w);
    *(short8*)(Xb + (size_t)i*8) = o;
  } else if (bid < 5632){
    int t = (bid - 4096)*256 + threadIdx.x;
    int n = t >> 7, kc = t & 127;
    int which = n >> 10, hd = n & 1023, h = hd >> 6, d = hd & 63;
    const float* W = which==0 ? Wq : (which==1 ? Wk : Wv);
    const float* src = W + ((size_t)h*1024 + kc*8)*64 + d;
    short8 o;
    #pragma unroll
    for (int j=0;j<8;++j) o[j] = (short)f2bf(src[(size_t)j*64]);
    *(short8*)(Wp + (size_t)n*1024 + kc*8) = o;
  } else {
    int t = (bid - 5632)*256 + threadIdx.x;
    int n = t >> 7, kc = t & 127;
    const float* src = Wo + (size_t)(kc*8)*1024 + n;
    short8 o;
    #pragma unroll
    for (int j=0;j<8;++j) o[j] = (short)f2bf(src[(size_t)j*1024]);
    *(short8*)(WoT + (size_t)n*1024 + kc*8) = o;
  }
}

// ------- merged GEMM1: blocks 0-255 QK (256x256), blocks 256-511 V (128x256) -------
__global__ __launch_bounds__(512)
void gemm_qkv(const short* __restrict__ A, const short* __restrict__ Bt,
              const float* __restrict__ bq, const float* __restrict__ bk,
              const float* __restrict__ bv,
              short* __restrict__ Qb, short* __restrict__ Kb, short* __restrict__ Vtb)
{
  __shared__ __align__(16) char smraw[147456];
  const int K2 = 2048;
  int t = threadIdx.x, lane = t & 63, wid = t >> 6;
  int l15 = lane & 15, l4 = lane >> 4;

  if (blockIdx.x < 256){
    // ---------- QK path: 256x256 tile, BK=64, 2-buf, counted vmcnt(8) ----------
    int wr = wid >> 2, wc = wid & 3;
    int swz = (blockIdx.x & 7) * 32 + (blockIdx.x >> 3);   // 256 blocks, XCD swizzle
    int bm = swz & 31, bn = swz >> 5;                      // 32 x 8
    size_t abase = (size_t)bm * 256 * K2;
    size_t bbase = (size_t)bn * 256 * K2;
    char* sm0 = smraw;
    char* sm1 = smraw + 65536;

    f32x4 acc[8][4] = {};
    bf16x8 af[8], bfr[4];
    const char* sA; const char* sB;

    auto stageA = [&](int kt, char* buf){
      int kb = kt * 128;
      #pragma unroll
      for (int c = 0; c < 4; ++c){
        int x = c*8192 + t*16;
        int r = x >> 7, z = x & 127;
        int zs = z ^ ((r & 7) << 4);
        gl_lds16((const char*)A + abase + (size_t)r*K2 + kb + zs, buf + c*8192 + wid*1024);
      }
    };
    auto stageB = [&](int kt, char* buf){
      int kb = kt * 128;
      #pragma unroll
      for (int c = 0; c < 4; ++c){
        int x = c*8192 + t*16;
        int r = x >> 7, z = x & 127;
        int zs = z ^ ((r & 7) << 4);
        gl_lds16((const char*)Bt + bbase + (size_t)r*K2 + kb + zs, buf + 32768 + c*8192 + wid*1024);
      }
    };
    auto rd_af = [&](int kk){
      int cb = kk*64 + l4*16;
      #pragma unroll
      for (int i = 0; i < 8; ++i){
        int ra = wr*128 + i*16 + l15;
        af[i] = *(const bf16x8*)(sA + ra*128 + (cb ^ ((ra&7)<<4)));
      }
    };
    auto rd_bf = [&](int kk){
      int cb = kk*64 + l4*16;
      #pragma unroll
      for (int j = 0; j < 4; ++j){
        int rb = wc*64 + j*16 + l15;
        bfr[j] = *(const bf16x8*)(sB + rb*128 + (cb ^ ((rb&7)<<4)));
      }
    };
    auto mm = [&](){
      __builtin_amdgcn_s_setprio(1);
      #pragma unroll
      for (int i = 0; i < 8; ++i)
        #pragma unroll
        for (int j = 0; j < 4; ++j)
          acc[i][j] = __builtin_amdgcn_mfma_f32_16x16x32_bf16(af[i], bfr[j], acc[i][j], 0, 0, 0);
      __builtin_amdgcn_s_setprio(0);
    };

    stageA(0, sm0); stageB(0, sm0);

    for (int kt = 0; kt < 16; ++kt){
      BAR();
      if (kt < 15){
        char* nb = (kt & 1) ? sm0 : sm1;
        stageA(kt + 1, nb); stageB(kt + 1, nb);
        asm volatile("s_waitcnt vmcnt(8)" ::: "memory");
      } else {
        asm volatile("s_waitcnt vmcnt(0)" ::: "memory");
      }
      BAR();
      sA = (kt & 1) ? sm1 : sm0; sB = sA + 32768;
      rd_af(0); rd_bf(0);
      mm();
      rd_af(1); rd_bf(1);
      mm();
    }

    #pragma unroll
    for (int i = 0; i < 8; ++i){
      int mbase = bm*256 + wr*128 + i*16 + l4*4;
      #pragma unroll
      for (int j = 0; j < 4; ++j){
        int n = bn*256 + wc*64 + j*16 + l15;
        int which = n >> 10, hd = n & 1023, h = hd >> 6, d = hd & 63;
        float bias = (which==0 ? bq : bk)[hd];
        int b = mbase >> 11, sbase = mbase & 2047;
        size_t bh = (size_t)(b*16 + h);
        short* dst = (which==0 ? Qb : Kb) + bh*2048*64;
        float sc = which==0 ? 0.18033688f : 1.0f;   // Q: 1/sqrt(D)*log2(e)
        #pragma unroll
        for (int r = 0; r < 4; ++r)
          dst[(size_t)(sbase + r)*64 + d] = (short)f2bf((acc[i][j][r] + bias) * sc);
      }
    }
  } else {
    // ---------- V path: 128x256 tile, 3-buf dist-2, counted vmcnt(6) ----------
    const short* Bv = Bt + (size_t)2048*1024;
    int bid = blockIdx.x - 256;
    int wr = wid >> 2, wc = wid & 3;
    int swz = (bid & 7) * 32 + (bid >> 3);                 // 256 blocks
    int bm = swz & 63, bn = swz >> 6;                      // 64 x 4
    size_t abase = (size_t)bm * 128 * K2;
    size_t bbase = (size_t)bn * 256 * K2;

    f32x4 acc[4][4] = {};
    const char* sA; const char* sB;
    bf16x8 af[4], bfr[4];

    auto buf3 = [&](int i){ return smraw + i*49152; };

    auto stageA = [&](int kt, char* buf){
      int kb = kt * 128;
      #pragma unroll
      for (int c = 0; c < 2; ++c){
        int x = c*8192 + t*16;
        int r = x >> 7, z = x & 127;
        int zs = z ^ ((r & 7) << 4);
        gl_lds16((const char*)A + abase + (size_t)r*K2 + kb + zs, buf + c*8192 + wid*1024);
      }
    };
    auto stageB = [&](int kt, char* buf, int c0){
      int kb = kt * 128;
      #pragma unroll
      for (int c = 0; c < 2; ++c){
        int cc = c0 + c;
        int x = cc*8192 + t*16;
        int r = x >> 7, z = x & 127;
        int zs = z ^ ((r & 7) << 4);
        gl_lds16((const char*)Bv + bbase + (size_t)r*K2 + kb + zs, buf + 16384 + cc*8192 + wid*1024);
      }
    };
    auto rd_af = [&](int kk){
      int cb = kk*64 + l4*16;
      #pragma unroll
      for (int i = 0; i < 4; ++i){
        int ra = wr*64 + i*16 + l15;
        af[i] = *(const bf16x8*)(sA + ra*128 + (cb ^ ((ra&7)<<4)));
      }
    };
    auto rd_bf = [&](int kk, int j0){
      int cb = kk*64 + l4*16;
      #pragma unroll
      for (int j = 0; j < 2; ++j){
        int rb = wc*64 + (j0 + j)*16 + l15;
        bfr[j0 + j] = *(const bf16x8*)(sB + rb*128 + (cb ^ ((rb&7)<<4)));
      }
    };
    auto mm = [&](int j0){
      __builtin_amdgcn_s_setprio(1);
      #pragma unroll
      for (int i = 0; i < 4; ++i)
        #pragma unroll
        for (int j = 0; j < 2; ++j)
          acc[i][j0+j] = __builtin_amdgcn_mfma_f32_16x16x32_bf16(af[i], bfr[j0+j], acc[i][j0+j], 0, 0, 0);
      __builtin_amdgcn_s_setprio(0);
    };

    stageA(0, buf3(0)); stageB(0, buf3(0), 0); stageB(0, buf3(0), 2);
    stageA(1, buf3(1)); stageB(1, buf3(1), 0); stageB(1, buf3(1), 2);

    for (int kt = 0; kt < 16; ++kt){
      if (kt == 15) asm volatile("s_waitcnt vmcnt(0)" ::: "memory");
      else          asm volatile("s_waitcnt vmcnt(6)" ::: "memory");
      BAR();
      sA = buf3(kt % 3); sB = sA + 16384;
      char* nb = buf3((kt + 2) % 3);
      bool st = kt < 14;
      rd_af(0); rd_bf(0, 0);
      if (st) stageA(kt + 2, nb);
      BAR(); mm(0); BAR();
      rd_bf(0, 2);
      if (st) stageB(kt + 2, nb, 0);
      BAR(); mm(2); BAR();
      rd_af(1); rd_bf(1, 0);
      if (st) stageB(kt + 2, nb, 2);
      BAR(); mm(0); BAR();
      rd_bf(1, 2);
      BAR(); mm(2);
    }

    #pragma unroll
    for (int i = 0; i < 4; ++i){
      int mbase = bm*128 + wr*64 + i*16 + l4*4;
      #pragma unroll
      for (int j = 0; j < 4; ++j){
        int n = bn*256 + wc*64 + j*16 + l15;   // n == h*64+d in [0,1024)
        int h = n >> 6, d = n & 63;
        float bias = bv[n];
        int b = mbase >> 11, sbase = mbase & 2047;
        size_t bh = (size_t)(b*16 + h);
        ushort4v pv;
        #pragma unroll
        for (int r = 0; r < 4; ++r) pv[r] = f2bf(acc[i][j][r] + bias);
        *(ushort4v*)(Vtb + (bh*64 + d)*2048 + sbase) = pv;
      }
    }
  }
}

// ------- GEMM2: Out[8192][1024] = Ob * WoT^T (128x256, 3-buf dist-2 vmcnt(6)) -------
__global__ __launch_bounds__(512)
void gemm_out(const short* __restrict__ A, const short* __restrict__ Bt,
              const float* __restrict__ b0, float* __restrict__ Out)
{
  __shared__ __align__(16) char sm[3][49152];
  const int K2 = 2048;
  int t = threadIdx.x, lane = t & 63, wid = t >> 6;
  int wr = wid >> 2, wc = wid & 3;
  int l15 = lane & 15, l4 = lane >> 4;
  int swz = (blockIdx.x & 7) * 32 + (blockIdx.x >> 3);   // 256 blocks
  int bm = swz & 63, bn = swz >> 6;
  size_t abase = (size_t)bm * 128 * K2;
  size_t bbase = (size_t)bn * 256 * K2;

  f32x4 acc[4][4] = {};
  const char* sA; const char* sB;
  bf16x8 af[4], bfr[4];

  auto stageA = [&](int kt, char* buf){
    int kb = kt * 128;
    #pragma unroll
    for (int c = 0; c < 2; ++c){
      int x = c*8192 + t*16;
      int r = x >> 7, z = x & 127;
      int zs = z ^ ((r & 7) << 4);
      gl_lds16((const char*)A + abase + (size_t)r*K2 + kb + zs, buf + c*8192 + wid*1024);
    }
  };
  auto stageB = [&](int kt, char* buf, int c0){
    int kb = kt * 128;
    #pragma unroll
    for (int c = 0; c < 2; ++c){
      int cc = c0 + c;
      int x = cc*8192 + t*16;
      int r = x >> 7, z = x & 127;
      int zs = z ^ ((r & 7) << 4);
      gl_lds16((const char*)Bt + bbase + (size_t)r*K2 + kb + zs, buf + 16384 + cc*8192 + wid*1024);
    }
  };
  auto rd_af = [&](int kk){
    int cb = kk*64 + l4*16;
    #pragma unroll
    for (int i = 0; i < 4; ++i){
      int ra = wr*64 + i*16 + l15;
      af[i] = *(const bf16x8*)(sA + ra*128 + (cb ^ ((ra&7)<<4)));
    }
  };
  auto rd_bf = [&](int kk, int j0){
    int cb = kk*64 + l4*16;
    #pragma unroll
    for (int j = 0; j < 2; ++j){
      int rb = wc*64 + (j0 + j)*16 + l15;
      bfr[j0 + j] = *(const bf16x8*)(sB + rb*128 + (cb ^ ((rb&7)<<4)));
    }
  };
  auto mm = [&](int j0){
    __builtin_amdgcn_s_setprio(1);
    #pragma unroll
    for (int i = 0; i < 4; ++i)
      #pragma unroll
      for (int j = 0; j < 2; ++j)
        acc[i][j0+j] = __builtin_amdgcn_mfma_f32_16x16x32_bf16(af[i], bfr[j0+j], acc[i][j0+j], 0, 0, 0);
    __builtin_amdgcn_s_setprio(0);
  };

  stageA(0, sm[0]); stageB(0, sm[0], 0); stageB(0, sm[0], 2);
  stageA(1, sm[1]); stageB(1, sm[1], 0); stageB(1, sm[1], 2);

  for (int kt = 0; kt < 16; ++kt){
    if (kt == 15) asm volatile("s_waitcnt vmcnt(0)" ::: "memory");
    else          asm volatile("s_waitcnt vmcnt(6)" ::: "memory");
    BAR();
    sA = sm[kt % 3]; sB = sA + 16384;
    char* nb = sm[(kt + 2) % 3];
    bool st = kt < 14;
    rd_af(0); rd_bf(0, 0);
    if (st) stageA(kt + 2, nb);
    BAR(); mm(0); BAR();
    rd_bf(0, 2);
    if (st) stageB(kt + 2, nb, 0);
    BAR(); mm(2); BAR();
    rd_af(1); rd_bf(1, 0);
    if (st) stageB(kt + 2, nb, 2);
    BAR(); mm(0); BAR();
    rd_bf(1, 2);
    BAR(); mm(2);
  }

  #pragma unroll
  for (int i = 0; i < 4; ++i){
    int mbase = bm*128 + wr*64 + i*16 + l4*4;
    #pragma unroll
    for (int j = 0; j < 4; ++j){
      int n = bn*256 + wc*64 + j*16 + l15;
      float bias = b0[n];
      #pragma unroll
      for (int r = 0; r < 4; ++r)
        Out[(size_t)(mbase + r)*1024 + n] = acc[i][j][r] + bias;
    }
  }
}

// ---------------- causal flash attention ----------------
// grid: 2048 blocks = 32 q-chunks (LPT) x 64 bh; 4 waves x 16 q-rows (QBLK=64).
// Swapped QK^T; P in registers via permlane swaps; fixed-shift softmax
// (P=exp2(s) directly, l via all-ones MFMA; masked -> exp2(-1e30)=0).
__global__ __launch_bounds__(256, 5)
void attn(const short* __restrict__ Qb, const short* __restrict__ Kb,
          const short* __restrict__ Vtb, short* __restrict__ Ob)
{
  __shared__ __align__(16) char smK[2][8192];
  __shared__ __align__(16) char smV[2][8192];
  int t = threadIdx.x, lane = t & 63, wid = t >> 6;
  int l15 = lane & 15, hi = lane >> 4;
  int hi16 = hi*16, hi4 = hi*4;
  int bh = blockIdx.x & 63;
  int qb = 31 - (blockIdx.x >> 6);           // LPT: longest first
  int b = bh >> 4, h = bh & 15;
  int wq0 = qb*64 + wid*16;
  const char* Qh = (const char*)(Qb + (size_t)bh*2048*64);
  const char* Kh = (const char*)(Kb + (size_t)bh*2048*64);
  const char* Vh = (const char*)(Vtb + (size_t)bh*64*2048);

  bf16x8 vones;
  #pragma unroll
  for (int z = 0; z < 8; ++z) vones[z] = (__bf16)1.0f;

  bf16x8 qf[2];
  #pragma unroll
  for (int kk = 0; kk < 2; ++kk)
    qf[kk] = *(const bf16x8*)(Qh + (size_t)(wq0 + l15)*128 + kk*64 + hi16);

  f32x4 oacc[4] = {};
  f32x4 lacc = {};

  int nkt = qb + 1;

  #pragma unroll
  for (int c = 0; c < 2; ++c){
    int x = c*4096 + t*16;
    int r = x >> 7, z = x & 127;
    int zs = z ^ ((r & 7) << 4);
    gl_lds16(Kh + (size_t)r*128 + zs, smK[0] + c*4096 + wid*1024);
    gl_lds16(Vh + (size_t)r*4096 + zs, smV[0] + c*4096 + wid*1024);
  }
  __syncthreads();

  for (int kt = 0; kt < nkt; ++kt){
    int cur = kt & 1;
    if (kt + 1 < nkt){
      int nxt = cur ^ 1;
      #pragma unroll
      for (int c = 0; c < 2; ++c){
        int x = c*4096 + t*16;
        int r = x >> 7, z = x & 127;
        int zs = z ^ ((r & 7) << 4);
        gl_lds16(Kh + (size_t)(kt+1)*8192 + (size_t)r*128 + zs, smK[nxt] + c*4096 + wid*1024);
        gl_lds16(Vh + (size_t)r*4096 + (size_t)(kt+1)*128 + zs, smV[nxt] + c*4096 + wid*1024);
      }
    }
    const char* Kc = smK[cur];
    const char* Vc = smV[cur];
    int kbase = kt * 64;

    f32x4 sa[4];
    __builtin_amdgcn_s_setprio(1);
    #pragma unroll
    for (int nt = 0; nt < 4; ++nt){
      f32x4 a = {};
      #pragma unroll
      for (int kk = 0; kk < 2; ++kk){
        int rk = nt*16 + l15;
        bf16x8 kf = *(const bf16x8*)(Kc + rk*128 + ((kk*64 + hi16) ^ ((rk&7)<<4)));
        a = __builtin_amdgcn_mfma_f32_16x16x32_bf16(kf, qf[kk], a, 0, 0, 0);
      }
      sa[nt] = a;
    }
    __builtin_amdgcn_s_setprio(0);

    if (kt == qb){
      int qrow = wq0 + l15;
      #pragma unroll
      for (int nt = 0; nt < 4; ++nt)
        #pragma unroll
        for (int r = 0; r < 4; ++r)
          if (kbase + nt*16 + hi4 + r > qrow) sa[nt][r] = -1e30f;
    }

    unsigned pw[8];
    #pragma unroll
    for (int nt = 0; nt < 4; ++nt){
      float p0 = exp2f(sa[nt][0]);
      float p1 = exp2f(sa[nt][1]);
      float p2 = exp2f(sa[nt][2]);
      float p3 = exp2f(sa[nt][3]);
      pw[nt*2]   = cvt_pk_bf16(p0, p1);
      pw[nt*2+1] = cvt_pk_bf16(p2, p3);
    }

    union U { unsigned u[4]; bf16x8 v; } f0, f1;
    {
      unsigned a0 = pw[0], b0v = pw[2];
      permlane32_swap(a0, b0v); permlane16_swap(a0, b0v);
      unsigned a1 = pw[1], b1v = pw[3];
      permlane32_swap(a1, b1v); permlane16_swap(a1, b1v);
      f0.u[0] = a0; f0.u[1] = a1; f0.u[2] = b0v; f0.u[3] = b1v;
      unsigned a2 = pw[4], b2v = pw[6];
      permlane32_swap(a2, b2v); permlane16_swap(a2, b2v);
      unsigned a3 = pw[5], b3v = pw[7];
      permlane32_swap(a3, b3v); permlane16_swap(a3, b3v);
      f1.u[0] = a2; f1.u[1] = a3; f1.u[2] = b2v; f1.u[3] = b3v;
    }

    __builtin_amdgcn_s_setprio(1);
    #pragma unroll
    for (int kk = 0; kk < 2; ++kk){
      bf16x8 pf = kk ? f1.v : f0.v;
      lacc = __builtin_amdgcn_mfma_f32_16x16x32_bf16(vones, pf, lacc, 0, 0, 0);
      #pragma unroll
      for (int dt = 0; dt < 4; ++dt){
        int rv = dt*16 + l15;
        bf16x8 vf = *(const bf16x8*)(Vc + rv*128 + ((kk*64 + hi16) ^ ((rv&7)<<4)));
        oacc[dt] = __builtin_amdgcn_mfma_f32_16x16x32_bf16(vf, pf, oacc[dt], 0, 0, 0);
      }
    }
    __builtin_amdgcn_s_setprio(0);

    __syncthreads();
  }

  float inv = 1.0f / lacc[0];
  int srow = wq0 + l15;
  size_t rb = ((size_t)(b*2048 + srow))*1024 + h*64 + hi4;
  #pragma unroll
  for (int dt = 0; dt < 4; ++dt){
    unsigned w0 = cvt_pk_bf16(oacc[dt][0]*inv, oacc[dt][1]*inv);
    unsigned w1 = cvt_pk_bf16(oacc[dt][2]*inv, oacc[dt][3]*inv);
    *(unsigned long long*)(Ob + rb + dt*16) =
        ((unsigned long long)w1 << 32) | (unsigned long long)w0;
  }
}

// ---------------- launch ----------------
extern "C" void kernel_launch(void* const* d_in, const int* in_sizes, int n_in,
                              void* d_out, int out_size, void* d_ws, size_t ws_size,
                              hipStream_t stream)
{
  const float* X  = (const float*)d_in[0];
  const float* Wq = (const float*)d_in[1];
  const float* Wk = (const float*)d_in[2];
  const float* Wv = (const float*)d_in[3];
  const float* bq = (const float*)d_in[4];
  const float* bk = (const float*)d_in[5];
  const float* bv = (const float*)d_in[6];
  const float* Wo = (const float*)d_in[7];
  const float* bo = (const float*)d_in[8];
  float* Out = (float*)d_out;

  char* ws = (char*)d_ws;
  short* Xbf  = (short*)(ws);
  short* Wp   = (short*)(ws + 16777216);
  short* WoT  = (short*)(ws + 23068672);
  short* Qb   = (short*)(ws + 25165824);
  short* Kb   = (short*)(ws + 41943040);
  short* Vtb  = (short*)(ws + 58720256);
  short* Ob   = (short*)(ws + 75497472);

  pack_all<<<6144, 256, 0, stream>>>(X, Wq, Wk, Wv, Wo, Xbf, Wp, WoT);

  gemm_qkv<<<512, 512, 0, stream>>>(Xbf, Wp, bq, bk, bv, Qb, Kb, Vtb);
  attn    <<<2048, 256, 0, stream>>>(Qb, Kb, Vtb, Ob);
  gemm_out<<<256, 512, 0, stream>>>(Ob, WoT, bo, Out);
}